// Round 2
// baseline (838.977 us; speedup 1.0000x reference)
//
#include <hip/hip_runtime.h>
#include <math.h>

#define Bc 256
#define Tc 1024
#define RNN_DIMc 1024
#define ENC_DIMc 512
#define ATT_DIMc 128
#define NFILTc 32
#define KSIZEc 31
#define PADc 15
#define NQ 4               // t-quarters per batch row
#define QT (Tc / NQ)       // 256 t per quarter

typedef float f4v __attribute__((ext_vector_type(4)));

__device__ __forceinline__ float fast_tanh(float x) {
    x = fminf(15.f, fmaxf(-15.f, x));
    float z = __expf(2.f * x);
    return (z - 1.f) / (z + 1.f);
}

__device__ __forceinline__ float wave_reduce_max(float x) {
#pragma unroll
    for (int off = 32; off > 0; off >>= 1) x = fmaxf(x, __shfl_xor(x, off, 64));
    return x;
}

__device__ __forceinline__ float wave_reduce_sum(float x) {
#pragma unroll
    for (int off = 32; off > 0; off >>= 1) x += __shfl_xor(x, off, 64);
    return x;
}

// ---------------- Kernel 1: pq[b][a] = W_q[a,:] . query[b,:] ----------------
__global__ __launch_bounds__(128) void qproj_k(const float* __restrict__ query,
                                               const float* __restrict__ W_q,
                                               float* __restrict__ pq) {
    const int b = blockIdx.x;
    __shared__ float q[RNN_DIMc];
    for (int i = threadIdx.x; i < RNN_DIMc; i += 128) q[i] = query[b * RNN_DIMc + i];
    __syncthreads();
    const float* w = W_q + (size_t)threadIdx.x * RNN_DIMc;
    float acc = 0.f;
#pragma unroll 4
    for (int r = 0; r < RNN_DIMc; r += 4) {
        float4 wv = *(const float4*)(w + r);
        acc = fmaf(wv.x, q[r + 0], acc);
        acc = fmaf(wv.y, q[r + 1], acc);
        acc = fmaf(wv.z, q[r + 2], acc);
        acc = fmaf(wv.w, q[r + 3], acc);
    }
    pq[b * ATT_DIMc + threadIdx.x] = acc;
}

// ---------------- Kernel 2: per-quarter energies + partial softmax + partial context ----------------
// grid = B*NQ (1024 blocks, 4/CU -> load balancing + inter-block phase overlap),
// block = 256 threads (one t per thread).
__global__ __launch_bounds__(256, 4) void lsa_main(
    const float* __restrict__ memory, const float* __restrict__ pm,
    const float* __restrict__ attn_w, const float* __restrict__ cum_w,
    const int* __restrict__ lens, const float* __restrict__ conv_w,
    const float* __restrict__ W_loc, const float* __restrict__ pq_g,
    const float* __restrict__ v_w, const float* __restrict__ v_b,
    float* __restrict__ p_buf, float* __restrict__ m_buf,
    float* __restrict__ s_buf, float* __restrict__ ctx_buf) {
    const int bq = blockIdx.x;
    const int b = bq >> 2;
    const int q = bq & 3;
    const int t0 = q * QT;
    const int tid = threadIdx.x;
    const int len = lens[b];

    __shared__ float s_pq[ATT_DIMc];          // 0.5 KiB
    __shared__ float s_win0[QT + 2 * PADc];   // 1.1 KiB attn window
    __shared__ float s_win1[QT + 2 * PADc];   // 1.1 KiB cum window
    __shared__ float s_attn[QT];              // 1 KiB  (unnormalized p)
    __shared__ float s_red[4];
    __shared__ float s_ctx[4][ENC_DIMc];      // 8 KiB ctx partials

    // ---- stage pq + padded windows for this quarter ----
    if (tid < ATT_DIMc) s_pq[tid] = pq_g[b * ATT_DIMc + tid];
    for (int i = tid; i < QT + 2 * PADc; i += 256) {
        int tt = t0 + i - PADc;
        bool ok = (tt >= 0) && (tt < Tc);
        s_win0[i] = ok ? attn_w[b * Tc + tt] : 0.f;
        s_win1[i] = ok ? cum_w[b * Tc + tt] : 0.f;
    }
    __syncthreads();

    // ---- energies e[t] (conv -> dense -> tanh -> v.h), masked skip ----
    const int t = t0 + tid;
    float e = -INFINITY;
    if (t < len) {
        float loc[NFILTc];
#pragma unroll
        for (int f = 0; f < NFILTc; ++f) loc[f] = 0.f;
        for (int k = 0; k < KSIZEc; ++k) {
            const float wa = s_win0[tid + k];
            const float wc = s_win1[tid + k];
#pragma unroll
            for (int f = 0; f < NFILTc; ++f) {
                loc[f] = fmaf(conv_w[f * (2 * KSIZEc) + k], wa, loc[f]);
                loc[f] = fmaf(conv_w[f * (2 * KSIZEc) + KSIZEc + k], wc, loc[f]);
            }
        }
        const float* pmrow = pm + ((size_t)(b * Tc + t)) * ATT_DIMc;
        float acc = 0.f;
#pragma unroll 2
        for (int a = 0; a < ATT_DIMc; a += 4) {
            const f4v pmv = __builtin_nontemporal_load((const f4v*)(pmrow + a));
            const float* wl = W_loc + a * NFILTc;
            float pl0 = 0.f, pl1 = 0.f, pl2 = 0.f, pl3 = 0.f;
#pragma unroll
            for (int f = 0; f < NFILTc; ++f) {
                float lf = loc[f];
                pl0 = fmaf(wl[f], lf, pl0);
                pl1 = fmaf(wl[NFILTc + f], lf, pl1);
                pl2 = fmaf(wl[2 * NFILTc + f], lf, pl2);
                pl3 = fmaf(wl[3 * NFILTc + f], lf, pl3);
            }
            acc = fmaf(v_w[a + 0], fast_tanh(s_pq[a + 0] + pl0 + pmv.x), acc);
            acc = fmaf(v_w[a + 1], fast_tanh(s_pq[a + 1] + pl1 + pmv.y), acc);
            acc = fmaf(v_w[a + 2], fast_tanh(s_pq[a + 2] + pl2 + pmv.z), acc);
            acc = fmaf(v_w[a + 3], fast_tanh(s_pq[a + 3] + pl3 + pmv.w), acc);
        }
        e = acc + v_b[0];
    }

    // ---- quarter-local softmax partials: m_q, p = exp(e - m_q), s_q ----
    {
        float m = wave_reduce_max(e);
        if ((tid & 63) == 0) s_red[tid >> 6] = m;
        __syncthreads();
        const float mq = fmaxf(fmaxf(s_red[0], s_red[1]), fmaxf(s_red[2], s_red[3]));
        const float p = (t < len) ? __expf(e - mq) : 0.f;  // guards m_q == -inf
        float s = wave_reduce_sum(p);
        __syncthreads();
        if ((tid & 63) == 0) s_red[tid >> 6] = s;
        __syncthreads();
        const float sq = s_red[0] + s_red[1] + s_red[2] + s_red[3];
        p_buf[b * Tc + t] = p;
        s_attn[tid] = p;
        if (tid == 0) {
            m_buf[b * NQ + q] = mq;
            s_buf[b * NQ + q] = sq;
        }
    }
    __syncthreads();

    // ---- partial context: ctx_q = sum_{t in quarter, t<len} p[t] * memory[b,t,:] ----
    {
        const int tr = tid >> 6;          // 0..3 : wave id = t-residue
        const int e8 = (tid & 63) * 8;    // 0..504
        const float* mb = memory + (size_t)b * Tc * ENC_DIMc + (size_t)t0 * ENC_DIMc;
        int lim = len - t0;
        lim = lim < 0 ? 0 : (lim > QT ? QT : lim);
        f4v acc0 = {0.f, 0.f, 0.f, 0.f};
        f4v acc1 = {0.f, 0.f, 0.f, 0.f};
#pragma unroll 4
        for (int tt = tr; tt < lim; tt += 4) {
            const float w = s_attn[tt];   // wave-uniform broadcast
            const float* row = mb + (size_t)tt * ENC_DIMc + e8;
            const f4v m0 = __builtin_nontemporal_load((const f4v*)(row));
            const f4v m1 = __builtin_nontemporal_load((const f4v*)(row + 4));
            acc0.x = fmaf(w, m0.x, acc0.x);
            acc0.y = fmaf(w, m0.y, acc0.y);
            acc0.z = fmaf(w, m0.z, acc0.z);
            acc0.w = fmaf(w, m0.w, acc0.w);
            acc1.x = fmaf(w, m1.x, acc1.x);
            acc1.y = fmaf(w, m1.y, acc1.y);
            acc1.z = fmaf(w, m1.z, acc1.z);
            acc1.w = fmaf(w, m1.w, acc1.w);
        }
        *(f4v*)&s_ctx[tr][e8] = acc0;
        *(f4v*)&s_ctx[tr][e8 + 4] = acc1;
    }
    __syncthreads();
    for (int e2 = tid; e2 < ENC_DIMc; e2 += 256) {
        float v = s_ctx[0][e2] + s_ctx[1][e2] + s_ctx[2][e2] + s_ctx[3][e2];
        ctx_buf[(size_t)(b * NQ + q) * ENC_DIMc + e2] = v;
    }
}

// ---------------- Kernel 3: flash-style combine across quarters ----------------
__global__ __launch_bounds__(512) void lsa_comb(
    const float* __restrict__ p_buf, const float* __restrict__ m_buf,
    const float* __restrict__ s_buf, const float* __restrict__ ctx_buf,
    const float* __restrict__ cum_w, float* __restrict__ ctx,
    float* __restrict__ out_attn, float* __restrict__ out_cum) {
    const int b = blockIdx.x;
    const int tid = threadIdx.x;

    const float m0 = m_buf[b * NQ + 0], m1 = m_buf[b * NQ + 1];
    const float m2 = m_buf[b * NQ + 2], m3 = m_buf[b * NQ + 3];
    const float M = fmaxf(fmaxf(m0, m1), fmaxf(m2, m3));
    const float ex0 = (m0 == -INFINITY) ? 0.f : __expf(m0 - M);
    const float ex1 = (m1 == -INFINITY) ? 0.f : __expf(m1 - M);
    const float ex2 = (m2 == -INFINITY) ? 0.f : __expf(m2 - M);
    const float ex3 = (m3 == -INFINITY) ? 0.f : __expf(m3 - M);
    const float S = s_buf[b * NQ + 0] * ex0 + s_buf[b * NQ + 1] * ex1 +
                    s_buf[b * NQ + 2] * ex2 + s_buf[b * NQ + 3] * ex3;
    const float inv = 1.f / S;

    // weights: t = tid (quarters 0/1) and t = tid + 512 (quarters 2/3)
    {
        const int tA = tid;
        const float exA = (tA >> 8) ? ex1 : ex0;
        const float naA = p_buf[b * Tc + tA] * exA * inv;
        out_attn[b * Tc + tA] = naA;
        out_cum[b * Tc + tA] = cum_w[b * Tc + tA] + naA;

        const int tB = tid + 512;
        const float exB = (tid >> 8) ? ex3 : ex2;
        const float naB = p_buf[b * Tc + tB] * exB * inv;
        out_attn[b * Tc + tB] = naB;
        out_cum[b * Tc + tB] = cum_w[b * Tc + tB] + naB;
    }
    // context: rescale + reduce the 4 partials
    if (tid < ENC_DIMc) {
        const size_t base = (size_t)(b * NQ) * ENC_DIMc + tid;
        float v = ctx_buf[base] * ex0 + ctx_buf[base + ENC_DIMc] * ex1 +
                  ctx_buf[base + 2 * ENC_DIMc] * ex2 + ctx_buf[base + 3 * ENC_DIMc] * ex3;
        ctx[b * ENC_DIMc + tid] = v * inv;
    }
}

extern "C" void kernel_launch(void* const* d_in, const int* in_sizes, int n_in,
                              void* d_out, int out_size, void* d_ws, size_t ws_size,
                              hipStream_t stream) {
    const float* query  = (const float*)d_in[0];
    const float* memory = (const float*)d_in[1];
    const float* pm     = (const float*)d_in[2];
    const float* attn_w = (const float*)d_in[3];
    const float* cum_w  = (const float*)d_in[4];
    const int*   lens   = (const int*)d_in[5];
    const float* conv_w = (const float*)d_in[6];
    const float* W_loc  = (const float*)d_in[7];
    const float* W_q    = (const float*)d_in[8];
    const float* v_w    = (const float*)d_in[9];
    const float* v_b    = (const float*)d_in[10];

    float* out      = (float*)d_out;
    float* ctx      = out;                              // B*ENC_DIM
    float* out_attn = out + Bc * ENC_DIMc;              // B*T
    float* out_cum  = out + Bc * ENC_DIMc + Bc * Tc;    // B*T

    // workspace layout (floats)
    float* ws      = (float*)d_ws;
    float* pq      = ws;                                 // B*128
    float* p_buf   = pq + Bc * ATT_DIMc;                 // B*T
    float* m_buf   = p_buf + Bc * Tc;                    // B*NQ
    float* s_buf   = m_buf + Bc * NQ;                    // B*NQ
    float* ctx_buf = s_buf + Bc * NQ;                    // B*NQ*ENC_DIM

    qproj_k<<<Bc, 128, 0, stream>>>(query, W_q, pq);
    lsa_main<<<Bc * NQ, 256, 0, stream>>>(memory, pm, attn_w, cum_w, lens,
                                          conv_w, W_loc, pq, v_w, v_b,
                                          p_buf, m_buf, s_buf, ctx_buf);
    lsa_comb<<<Bc, 512, 0, stream>>>(p_buf, m_buf, s_buf, ctx_buf, cum_w,
                                     ctx, out_attn, out_cum);
}

// Round 3
// 818.132 us; speedup vs baseline: 1.0255x; 1.0255x over previous
//
#include <hip/hip_runtime.h>
#include <math.h>

#define Bc 256
#define Tc 1024
#define RNN_DIMc 1024
#define ENC_DIMc 512
#define ATT_DIMc 128
#define NFILTc 32
#define KSIZEc 31
#define PADc 15
#define NCH 16             // context t-chunks per batch row
#define CHT (Tc / NCH)     // 64 rows per chunk

typedef float f4v __attribute__((ext_vector_type(4)));

__device__ __forceinline__ float fast_tanh(float x) {
    x = fminf(15.f, fmaxf(-15.f, x));
    float z = __expf(2.f * x);
    return (z - 1.f) / (z + 1.f);
}

__device__ __forceinline__ float wave_reduce_max(float x) {
#pragma unroll
    for (int off = 32; off > 0; off >>= 1) x = fmaxf(x, __shfl_xor(x, off, 64));
    return x;
}

__device__ __forceinline__ float wave_reduce_sum(float x) {
#pragma unroll
    for (int off = 32; off > 0; off >>= 1) x += __shfl_xor(x, off, 64);
    return x;
}

// ---------------- Kernel A: qproj + energies + softmax -> out_attn/out_cum ----------------
// One block per b (proven R1 structure, phase 4 removed).
__global__ __launch_bounds__(1024) void lsa_energy(
    const float* __restrict__ query, const float* __restrict__ pm,
    const float* __restrict__ attn_w, const float* __restrict__ cum_w,
    const int* __restrict__ lens, const float* __restrict__ conv_w,
    const float* __restrict__ W_loc, const float* __restrict__ W_q,
    const float* __restrict__ v_w, const float* __restrict__ v_b,
    float* __restrict__ out_attn, float* __restrict__ out_cum) {
    const int b = blockIdx.x;
    const int tid = threadIdx.x;
    const int len = lens[b];

    __shared__ float s_q[RNN_DIMc];              // 4 KiB   query row
    __shared__ float s_pq[ATT_DIMc];             // 0.5 KiB
    __shared__ float s_win0[Tc + 2 * PADc];      // 4.2 KiB attn window
    __shared__ float s_win1[Tc + 2 * PADc];      // 4.2 KiB cum window
    __shared__ float s_redm[16];
    __shared__ float s_reds[16];

    // ---- Phase 0a: stage query row + padded windows ----
    s_q[tid] = query[b * RNN_DIMc + tid];
    for (int i = tid; i < Tc + 2 * PADc; i += 1024) {
        int tt = i - PADc;
        bool ok = (tt >= 0) && (tt < Tc);
        s_win0[i] = ok ? attn_w[b * Tc + tt] : 0.f;
        s_win1[i] = ok ? cum_w[b * Tc + tt] : 0.f;
    }
    __syncthreads();

    // ---- Phase 0b: pq[a] = W_q[a,:] . q ----
    {
        const int a = tid >> 3;
        const int c = tid & 7;
        const float* w = W_q + (size_t)a * RNN_DIMc;
        float acc = 0.f;
#pragma unroll 4
        for (int j = 0; j < 32; ++j) {
            const int r = c * 4 + j * 32;
            float4 wv = *(const float4*)(w + r);
            acc = fmaf(wv.x, s_q[r + 0], acc);
            acc = fmaf(wv.y, s_q[r + 1], acc);
            acc = fmaf(wv.z, s_q[r + 2], acc);
            acc = fmaf(wv.w, s_q[r + 3], acc);
        }
        acc += __shfl_xor(acc, 1, 64);
        acc += __shfl_xor(acc, 2, 64);
        acc += __shfl_xor(acc, 4, 64);
        if (c == 0) s_pq[a] = acc;
    }
    __syncthreads();

    // ---- Phase 2: energies e[t] (conv -> dense -> tanh -> v.h), masked skip ----
    const int t = tid;
    float e = -INFINITY;
    if (t < len) {
        float loc[NFILTc];
#pragma unroll
        for (int f = 0; f < NFILTc; ++f) loc[f] = 0.f;
        for (int k = 0; k < KSIZEc; ++k) {
            const float wa = s_win0[t + k];
            const float wc = s_win1[t + k];
#pragma unroll
            for (int f = 0; f < NFILTc; ++f) {
                loc[f] = fmaf(conv_w[f * (2 * KSIZEc) + k], wa, loc[f]);
                loc[f] = fmaf(conv_w[f * (2 * KSIZEc) + KSIZEc + k], wc, loc[f]);
            }
        }
        const float* pmrow = pm + ((size_t)(b * Tc + t)) * ATT_DIMc;
        float acc = 0.f;
#pragma unroll 2
        for (int a = 0; a < ATT_DIMc; a += 4) {
            const f4v pmv = __builtin_nontemporal_load((const f4v*)(pmrow + a));
            const float* wl = W_loc + a * NFILTc;
            float pl0 = 0.f, pl1 = 0.f, pl2 = 0.f, pl3 = 0.f;
#pragma unroll
            for (int f = 0; f < NFILTc; ++f) {
                float lf = loc[f];
                pl0 = fmaf(wl[f], lf, pl0);
                pl1 = fmaf(wl[NFILTc + f], lf, pl1);
                pl2 = fmaf(wl[2 * NFILTc + f], lf, pl2);
                pl3 = fmaf(wl[3 * NFILTc + f], lf, pl3);
            }
            acc = fmaf(v_w[a + 0], fast_tanh(s_pq[a + 0] + pl0 + pmv.x), acc);
            acc = fmaf(v_w[a + 1], fast_tanh(s_pq[a + 1] + pl1 + pmv.y), acc);
            acc = fmaf(v_w[a + 2], fast_tanh(s_pq[a + 2] + pl2 + pmv.z), acc);
            acc = fmaf(v_w[a + 3], fast_tanh(s_pq[a + 3] + pl3 + pmv.w), acc);
        }
        e = acc + v_b[0];
    }

    // ---- Phase 3: block softmax over t -> write normalized attn + cum ----
    {
        float m = wave_reduce_max(e);
        if ((tid & 63) == 0) s_redm[tid >> 6] = m;
        __syncthreads();
        float bm = s_redm[0];
#pragma unroll
        for (int j = 1; j < 16; ++j) bm = fmaxf(bm, s_redm[j]);

        float p = __expf(e - bm);  // masked: exp(-inf) == 0
        float s = wave_reduce_sum(p);
        if ((tid & 63) == 0) s_reds[tid >> 6] = s;
        __syncthreads();
        float tot = 0.f;
#pragma unroll
        for (int j = 0; j < 16; ++j) tot += s_reds[j];
        float na = p * (1.f / tot);

        out_attn[b * Tc + t] = na;
        out_cum[b * Tc + t] = s_win1[t + PADc] + na;
    }
}

// ---------------- Kernel B: context partials ----------------
// grid = B*NCH (4096 blocks, 8/CU -> hardware load balancing kills the len tail),
// block = 256. Each block: part[b][ch][:] = sum_{t in chunk, t<len} attn[t]*memory[b,t,:].
__global__ __launch_bounds__(256) void ctx_part_k(
    const float* __restrict__ memory, const float* __restrict__ out_attn,
    const int* __restrict__ lens, float* __restrict__ part) {
    const int bc = blockIdx.x;
    const int b = bc >> 4;
    const int ch = bc & (NCH - 1);
    const int t0 = ch * CHT;
    const int tid = threadIdx.x;
    const int len = lens[b];
    if (t0 >= len) return;  // reduce kernel consults lens; no zero-fill needed
    int lim = len - t0;
    if (lim > CHT) lim = CHT;

    __shared__ float s_w[CHT];
    __shared__ float s_part[4][ENC_DIMc];   // 8 KiB
    if (tid < CHT) s_w[tid] = out_attn[b * Tc + t0 + tid];
    __syncthreads();

    const int tr = tid >> 6;          // 0..3 : wave id = t-residue
    const int e8 = (tid & 63) * 8;    // 0..504
    const float* mb = memory + ((size_t)(b * Tc + t0)) * ENC_DIMc;
    f4v acc0 = {0.f, 0.f, 0.f, 0.f};
    f4v acc1 = {0.f, 0.f, 0.f, 0.f};
#pragma unroll 4
    for (int tt = tr; tt < lim; tt += 4) {
        const float w = s_w[tt];      // wave-uniform broadcast
        const float* row = mb + (size_t)tt * ENC_DIMc + e8;
        const f4v m0 = __builtin_nontemporal_load((const f4v*)(row));
        const f4v m1 = __builtin_nontemporal_load((const f4v*)(row + 4));
        acc0.x = fmaf(w, m0.x, acc0.x);
        acc0.y = fmaf(w, m0.y, acc0.y);
        acc0.z = fmaf(w, m0.z, acc0.z);
        acc0.w = fmaf(w, m0.w, acc0.w);
        acc1.x = fmaf(w, m1.x, acc1.x);
        acc1.y = fmaf(w, m1.y, acc1.y);
        acc1.z = fmaf(w, m1.z, acc1.z);
        acc1.w = fmaf(w, m1.w, acc1.w);
    }
    *(f4v*)&s_part[tr][e8] = acc0;
    *(f4v*)&s_part[tr][e8 + 4] = acc1;
    __syncthreads();
    for (int e2 = tid; e2 < ENC_DIMc; e2 += 256) {
        float v = s_part[0][e2] + s_part[1][e2] + s_part[2][e2] + s_part[3][e2];
        part[(size_t)bc * ENC_DIMc + e2] = v;
    }
}

// ---------------- Kernel C: reduce chunk partials -> ctx ----------------
__global__ __launch_bounds__(512) void ctx_comb_k(
    const float* __restrict__ part, const int* __restrict__ lens,
    float* __restrict__ ctx) {
    const int b = blockIdx.x;
    const int tid = threadIdx.x;
    const int nch = (lens[b] + CHT - 1) / CHT;  // chunks with t0 < len (8..16)
    const float* p = part + (size_t)(b * NCH) * ENC_DIMc + tid;
    float s = 0.f;
    for (int ch = 0; ch < nch; ++ch) s += p[(size_t)ch * ENC_DIMc];
    ctx[b * ENC_DIMc + tid] = s;
}

extern "C" void kernel_launch(void* const* d_in, const int* in_sizes, int n_in,
                              void* d_out, int out_size, void* d_ws, size_t ws_size,
                              hipStream_t stream) {
    const float* query  = (const float*)d_in[0];
    const float* memory = (const float*)d_in[1];
    const float* pm     = (const float*)d_in[2];
    const float* attn_w = (const float*)d_in[3];
    const float* cum_w  = (const float*)d_in[4];
    const int*   lens   = (const int*)d_in[5];
    const float* conv_w = (const float*)d_in[6];
    const float* W_loc  = (const float*)d_in[7];
    const float* W_q    = (const float*)d_in[8];
    const float* v_w    = (const float*)d_in[9];
    const float* v_b    = (const float*)d_in[10];

    float* out      = (float*)d_out;
    float* ctx      = out;                              // B*ENC_DIM
    float* out_attn = out + Bc * ENC_DIMc;              // B*T
    float* out_cum  = out + Bc * ENC_DIMc + Bc * Tc;    // B*T

    float* part = (float*)d_ws;                         // B*NCH*ENC_DIM floats (8 MB)

    lsa_energy<<<Bc, 1024, 0, stream>>>(query, pm, attn_w, cum_w, lens,
                                        conv_w, W_loc, W_q, v_w, v_b,
                                        out_attn, out_cum);
    ctx_part_k<<<Bc * NCH, 256, 0, stream>>>(memory, out_attn, lens, part);
    ctx_comb_k<<<Bc, 512, 0, stream>>>(part, lens, ctx);
}